// Round 2
// baseline (13094.766 us; speedup 1.0000x reference)
//
#include <hip/hip_runtime.h>

// 2-layer LSTM, T=512, B=64, I=H=1024. Persistent-kernel version:
//   - 256 blocks (1 per CU), block b<128 = layer0 cols [8b,8b+8), b>=128 = layer1.
//   - Weight tile (32 rows x 2048 bf16 = 128 KiB) staged in LDS ONCE, XOR-swizzled.
//   - A-fragments read straight from global (L2) with depth-8 register prefetch.
//   - c state in registers across all 512 steps; h exchanged via global bf16 slots.
//   - Device-scope flag barrier between steps (release wbl2 / acquire inv for
//     cross-XCD visibility of h).
// R1 fix: swizzled ds_read address decomposition had a bit-6 carry bug
// ((kb*2 ^ swz) + ks*64 != (ks*64+kb*2) ^ swz when swz bit6 set). Now bit 6 of
// the swizzle is applied as ks^s6 via even/odd base pointers; bits 4-5 fold
// into the base. All ds_read offsets remain compile-time immediates.

#define T_STEPS 512
#define BATCH   64
#define HDIM    1024
#define BH      (BATCH * HDIM)     // 65536
#define LDS_BYTES (32 * 4096)      // 32 W-rows x 2048 bf16, xor-swizzled

typedef __bf16 bf16x8 __attribute__((ext_vector_type(8)));
typedef __bf16 bf16x4 __attribute__((ext_vector_type(4)));
typedef float  f32x4  __attribute__((ext_vector_type(4)));

__device__ __forceinline__ float sigm_(float x) { return 1.0f / (1.0f + __expf(-x)); }
__device__ __forceinline__ float tanh_(float x) {
    float e = __expf(-2.0f * fabsf(x));      // e in (0,1], no overflow
    float t = (1.0f - e) / (1.0f + e);
    return copysignf(t, x);
}

// Persistent kernel. Block = one layer-cell x 8 h-columns for the whole sequence.
// Per step: gates[64 x 32] = A[64 x 2048] * Wtile^T, via 64 k-subs of
// {1 global A-frag load, 2 swizzled ds_read_b128 B-frags, 2 MFMA 16x16x32}.
__global__ __launch_bounds__(256, 1) void lstm_persist(
    const __bf16* __restrict__ Xb,
    const __bf16* __restrict__ W0, const __bf16* __restrict__ W1,
    __bf16* __restrict__ h0s, __bf16* __restrict__ h1s,
    float* __restrict__ out, float* __restrict__ h0f,
    float* __restrict__ c0v, float* __restrict__ c1v,
    int* __restrict__ flags)
{
    extern __shared__ char smem[];
    const int bid   = blockIdx.x;
    const int tid   = threadIdx.x;
    const int layer = bid >> 7;          // 0..127 -> layer0, 128..255 -> layer1
    const int cb    = bid & 127;
    const int n0    = cb * 8;            // h-column base (8 cols per block)
    const __bf16* W = layer ? W1 : W0;

    // ---- stage weight tile into LDS once, xor-swizzled ----
    // local row lr = g*8 + c  <->  W row g*1024 + n0 + c.
    // stored byte = lr*4096 + ((orig_byte) ^ ((lr&7)<<4)), orig 16B-granular.
    for (int idx = tid; idx < 32 * 256; idx += 256) {
        int lr = idx >> 8, ch = idx & 255;
        int wrow = (lr >> 3) * 1024 + n0 + (lr & 7);
        bf16x8 v = *(const bf16x8*)(W + (size_t)wrow * 2048 + ch * 8);
        int db = lr * 4096 + ((ch * 16) ^ ((lr & 7) << 4));
        *(bf16x8*)(smem + db) = v;
    }
    __syncthreads();

    const int lane = tid & 63;
    const int wave = tid >> 6;
    const int arow = wave * 16 + (lane & 15);   // batch row of this lane's A-frag
    const int kb   = (lane >> 4) * 8;           // k element offset within a k-sub
    const int r0   = lane & 15;                 // B-frag row, n-tile 0 (gates i|j)
    const int r1   = 16 + r0;                   // B-frag row, n-tile 1 (gates f|o)
    // Read address must be r*4096 + ((ks*64 + kb*2) ^ ((r&7)<<4)).
    // bits 4-5 of the XOR fold into the base (no carries: result < 64);
    // bit 6 of the XOR == flipping bit 0 of ks -> even/odd base pointers.
    const int lo16 = (kb * 2) ^ ((r0 & 3) << 4);
    const int s6   = (r0 >> 2) & 1;
    const char* pb0 = smem + r0 * 4096 + lo16;
    const char* pb1 = smem + r1 * 4096 + lo16;   // r1&7 == r0&7: same lo16/s6
    const char* pb0e = pb0 + s6 * 64;            // even ks: (ks^s6) = ks+s6
    const char* pb0o = pb0 - s6 * 64;            // odd  ks: (ks^s6) = ks-s6
    const char* pb1e = pb1 + s6 * 64;
    const char* pb1o = pb1 - s6 * 64;

    const int  lr   = lane & 15;
    const bool lo   = lr < 8;                   // lo lanes hold i|f, hi lanes j|o
    const int  col  = n0 + (lr & 7);
    const int  mrow = wave * 16 + (lane >> 4) * 4;

    float creg0 = 0.0f, creg1 = 0.0f;           // c state, 2 cells per thread

    for (int s = 0; s <= T_STEPS; ++s) {
        const int en = layer ? (s >= 1) : (s < T_STEPS);
        if (en) {
            const int t = layer ? s - 1 : s;
            const __bf16* Ax = layer ? (h0s + (size_t)(s & 1) * BH)
                                     : (Xb  + (size_t)s * BH);
            const __bf16* Ah = layer ? (h1s + (size_t)(t & 1) * BH)
                                     : (h0s + (size_t)(s & 1) * BH);
            __bf16* hb = layer ? (h1s + (size_t)((t & 1) ^ 1) * BH)
                               : (h0s + (size_t)((s & 1) ^ 1) * BH);

            const __bf16* ax = Ax + arow * 1024 + kb;   // k-subs 0..31
            const __bf16* ah = Ah + arow * 1024 + kb;   // k-subs 32..63

            f32x4 acc0 = {}, acc1 = {};
            bf16x8 p[8];                                 // depth-8 A prefetch
            #pragma unroll
            for (int u = 0; u < 8; ++u) p[u] = *(const bf16x8*)(ax + u * 32);
            #pragma unroll
            for (int base = 0; base < 64; base += 8) {
                #pragma unroll
                for (int u = 0; u < 8; ++u) {
                    const int ks = base + u;
                    bf16x8 a = p[u];
                    const int pf = ks + 8;
                    if (pf < 32)      p[u] = *(const bf16x8*)(ax + pf * 32);
                    else if (pf < 64) p[u] = *(const bf16x8*)(ah + (pf - 32) * 32);
                    bf16x8 b0 = *(const bf16x8*)(((ks & 1) ? pb0o : pb0e) + ks * 64);
                    bf16x8 b1 = *(const bf16x8*)(((ks & 1) ? pb1o : pb1e) + ks * 64);
                    acc0 = __builtin_amdgcn_mfma_f32_16x16x32_bf16(a, b0, acc0, 0, 0, 0);
                    acc1 = __builtin_amdgcn_mfma_f32_16x16x32_bf16(a, b1, acc1, 0, 0, 0);
                }
            }

            // lanes l and l^8 hold {i,f} / {j,o} of the same (m,col); exchange,
            // then lo lanes update r=0,1 and hi lanes r=2,3.
            float q0[4], q1[4];
            #pragma unroll
            for (int r2 = 0; r2 < 4; ++r2) {
                q0[r2] = __shfl_xor(acc0[r2], 8, 64);
                q1[r2] = __shfl_xor(acc1[r2], 8, 64);
            }
            const int rb = lo ? 0 : 2;
            #pragma unroll
            for (int rr = 0; rr < 2; ++rr) {
                const int r2 = rb + rr;
                float gi = lo ? acc0[r2] : q0[r2];
                float gj = lo ? q0[r2]   : acc0[r2];
                float gf = lo ? acc1[r2] : q1[r2];
                float go = lo ? q1[r2]   : acc1[r2];
                float cold = rr ? creg1 : creg0;
                float cn = cold * sigm_(gf + 1.0f) + sigm_(gi) * tanh_(gj);
                float hn = sigm_(go) * tanh_(cn);
                if (rr) creg1 = cn; else creg0 = cn;
                const int m = mrow + r2;
                hb[m * HDIM + col] = (__bf16)hn;
                if (layer) out[(size_t)t * BH + m * HDIM + col] = hn;
                else if (s == T_STEPS - 1) h0f[m * HDIM + col] = hn;
                if (t == T_STEPS - 1) (layer ? c1v : c0v)[m * HDIM + col] = cn;
            }
        }

        if (s < T_STEPS) {
            // release: all h-writes of this block drained (syncthreads) then
            // flushed past XCD L2 by the agent-scope release store (buffer_wbl2).
            __syncthreads();
            if (tid == 0)
                __hip_atomic_store(&flags[bid], s + 1, __ATOMIC_RELEASE,
                                   __HIP_MEMORY_SCOPE_AGENT);
            // wait: every thread polls one flag; __syncthreads_and is the barrier.
            int ok;
            do {
                int v = __hip_atomic_load(&flags[tid], __ATOMIC_RELAXED,
                                          __HIP_MEMORY_SCOPE_AGENT);
                ok = __syncthreads_and(v >= s + 1);
                if (!ok) __builtin_amdgcn_s_sleep(2);
            } while (!ok);
            __builtin_amdgcn_fence(__ATOMIC_ACQUIRE, "agent");   // buffer_inv
        }
    }
}

// Wcat[n][k] = k<1024 ? Wx[n][k] : Wh[n][k-1024], fp32 -> bf16. 4 elems/thread.
__global__ void convW(const float* __restrict__ Wx, const float* __restrict__ Wh,
                      __bf16* __restrict__ dst) {
    int i = blockIdx.x * 256 + threadIdx.x;   // 0 .. 2097151
    int e = i * 4;
    int n = e >> 11;
    int k = e & 2047;
    const float* src = (k < 1024) ? (Wx + n * 1024 + k) : (Wh + n * 1024 + (k - 1024));
    float4 v = *(const float4*)src;
    bf16x4 o = { (__bf16)v.x, (__bf16)v.y, (__bf16)v.z, (__bf16)v.w };
    *(bf16x4*)(dst + e) = o;
}

__global__ void convX(const float* __restrict__ x, __bf16* __restrict__ dst) {
    int i = blockIdx.x * 256 + threadIdx.x;   // 0 .. 8388607
    int e = i * 4;
    float4 v = *(const float4*)(x + e);
    bf16x4 o = { (__bf16)v.x, (__bf16)v.y, (__bf16)v.z, (__bf16)v.w };
    *(bf16x4*)(dst + e) = o;
}

__global__ void initz(__bf16* h0s, __bf16* h1s, float* c0, float* c1,
                      float* h0f, int* flags) {
    int i = blockIdx.x * 256 + threadIdx.x;   // 0 .. 65535
    h0s[i] = (__bf16)0.0f;                    // slot 0 (read at s=0)
    h1s[i] = (__bf16)0.0f;
    c0[i] = 0.0f;                             // defensive: deterministic if
    c1[i] = 0.0f;                             // persist kernel ever no-ops
    h0f[i] = 0.0f;
    if (i < 256) flags[i] = 0;
}

__global__ void epilogue_k(float* __restrict__ out, const float* __restrict__ h0f,
                           const float* __restrict__ c0, const float* __restrict__ c1) {
    int i = blockIdx.x * 256 + threadIdx.x;   // 0 .. 65535
    float* hout = out + (size_t)T_STEPS * BH;
    hout[i]      = h0f[i];                               // h[0] = final h0
    hout[BH + i] = out[(size_t)(T_STEPS - 1) * BH + i];  // h[1] = out[T-1]
    float* cout = hout + 2 * BH;
    cout[i]      = c0[i];
    cout[BH + i] = c1[i];
}

extern "C" void kernel_launch(void* const* d_in, const int* in_sizes, int n_in,
                              void* d_out, int out_size, void* d_ws, size_t ws_size,
                              hipStream_t stream) {
    const float* x   = (const float*)d_in[0];
    const float* Wx0 = (const float*)d_in[1];
    const float* Wh0 = (const float*)d_in[2];
    const float* Wx1 = (const float*)d_in[3];
    const float* Wh1 = (const float*)d_in[4];
    float* out = (float*)d_out;

    // Workspace carve-up (~97.3 MB total)
    char* p = (char*)d_ws;
    __bf16* W0c = (__bf16*)p; p += (size_t)4096 * 2048 * 2;   // 16 MB
    __bf16* W1c = (__bf16*)p; p += (size_t)4096 * 2048 * 2;   // 16 MB
    __bf16* Xb  = (__bf16*)p; p += (size_t)T_STEPS * BH * 2;  // 64 MB
    __bf16* h0s = (__bf16*)p; p += (size_t)2 * BH * 2;        // ping-pong
    __bf16* h1s = (__bf16*)p; p += (size_t)2 * BH * 2;
    float*  c0v = (float*)p;  p += (size_t)BH * 4;
    float*  c1v = (float*)p;  p += (size_t)BH * 4;
    float*  h0f = (float*)p;  p += (size_t)BH * 4;
    int*  flags = (int*)p;    p += 256 * 4;

    hipFuncSetAttribute(reinterpret_cast<const void*>(lstm_persist),
                        hipFuncAttributeMaxDynamicSharedMemorySize, LDS_BYTES);

    convW<<<8192, 256, 0, stream>>>(Wx0, Wh0, W0c);
    convW<<<8192, 256, 0, stream>>>(Wx1, Wh1, W1c);
    convX<<<32768, 256, 0, stream>>>(x, Xb);
    initz<<<256, 256, 0, stream>>>(h0s, h1s, c0v, c1v, h0f, flags);

    lstm_persist<<<256, 256, LDS_BYTES, stream>>>(Xb, W0c, W1c, h0s, h1s,
                                                  out, h0f, c0v, c1v, flags);

    epilogue_k<<<256, 256, 0, stream>>>(out, h0f, c0v, c1v);
}